// Round 1
// baseline (983.962 us; speedup 1.0000x reference)
//
#include <hip/hip_runtime.h>

#define NN 100000
#define EE 1600000
#define DD 32
#define CC 2
#define NLAYERS 4
#define GG 512

// ---------------------------------------------------------------------------
// Edge scatter: agg[dst] += h[src].  Thread t -> (edge e = t>>5, dim d = t&31).
// 32 consecutive lanes share an edge: edge-index loads broadcast, h row loads
// and atomic destinations are 128B-contiguous per 32-lane group.
// ---------------------------------------------------------------------------
__global__ void scatter_kernel(const float* __restrict__ h,
                               const int* __restrict__ ei,
                               float* __restrict__ agg) {
    unsigned t = blockIdx.x * blockDim.x + threadIdx.x;   // < EE*DD (exact grid)
    unsigned e = t >> 5;
    unsigned d = t & 31u;
    int s  = ei[e];        // src
    int dn = ei[EE + e];   // dst
    atomicAdd(&agg[(size_t)dn * DD + d], h[(size_t)s * DD + d]);
}

// ---------------------------------------------------------------------------
// Per-node MLP: z = h + agg; z1 = relu(bn1(z@W1+b1)); z2 = z1@W2+b2;
// h = relu(bn_out(relu(bn2(z2)))).   8 nodes per 256-thread block-iteration,
// 32 lanes per node (lane = output dim).  Weights staged in LDS.
// ---------------------------------------------------------------------------
__global__ void node_update_kernel(float* __restrict__ h,
                                   const float* __restrict__ agg,
                                   const float* __restrict__ W1,
                                   const float* __restrict__ b1,
                                   const float* __restrict__ g1,
                                   const float* __restrict__ bt1,
                                   const float* __restrict__ W2,
                                   const float* __restrict__ b2,
                                   const float* __restrict__ g2,
                                   const float* __restrict__ bt2,
                                   const float* __restrict__ ng,
                                   const float* __restrict__ nb) {
    __shared__ float sW1[DD * DD];
    __shared__ float sW2[DD * DD];
    __shared__ float sp[8 * DD];       // b1,g1,bt1,b2,g2,bt2,ng,nb
    __shared__ float z1[8][DD];
    __shared__ float z2[8][DD];

    const int tid = threadIdx.x;
    for (int i = tid; i < DD * DD; i += 256) {
        sW1[i] = W1[i];
        sW2[i] = W2[i];
    }
    if (tid < DD) {
        sp[0 * DD + tid] = b1[tid];
        sp[1 * DD + tid] = g1[tid];
        sp[2 * DD + tid] = bt1[tid];
        sp[3 * DD + tid] = b2[tid];
        sp[4 * DD + tid] = g2[tid];
        sp[5 * DD + tid] = bt2[tid];
        sp[6 * DD + tid] = ng[tid];
        sp[7 * DD + tid] = nb[tid];
    }
    __syncthreads();

    const float invs = 1.0f / sqrtf(1.001f);   // BN: mean=0, var=1, eps=1e-3
    const int j = tid >> 5;       // node slot within block (0..7)
    const int d = tid & 31;       // output dim
    const int ngroups = NN / 8;   // 12500 (exact)

    for (int grp = blockIdx.x; grp < ngroups; grp += gridDim.x) {
        const int idx = grp * 8 * DD + tid;          // coalesced 256-float slab
        ((float*)z1)[tid] = h[idx] + agg[idx];
        __syncthreads();

        float acc = sp[0 * DD + d];
        #pragma unroll
        for (int k = 0; k < DD; ++k)
            acc += z1[j][k] * sW1[k * DD + d];
        float v = acc * (sp[1 * DD + d] * invs) + sp[2 * DD + d];
        v = fmaxf(v, 0.f);
        z2[j][d] = v;
        __syncthreads();

        float acc2 = sp[3 * DD + d];
        #pragma unroll
        for (int k = 0; k < DD; ++k)
            acc2 += z2[j][k] * sW2[k * DD + d];
        float w = acc2 * (sp[4 * DD + d] * invs) + sp[5 * DD + d];
        w = fmaxf(w, 0.f);
        w = w * (sp[6 * DD + d] * invs) + sp[7 * DD + d];
        w = fmaxf(w, 0.f);
        h[idx] = w;
        // no trailing sync needed: next iter writes z1 only, reads of z2 are
        // complete before the next first __syncthreads()
    }
}

// ---------------------------------------------------------------------------
// Pool + readout head for one hidden level:
//   score[g,c] += sum_{n in g} h[n,:] . Wd[:,c]
// 512 nodes per block; 32 lanes per node reduce via shfl; LDS score image
// accumulated with LDS atomics; nonzero entries flushed with global atomics.
// ---------------------------------------------------------------------------
__global__ void pool_kernel(const float* __restrict__ h,
                            const int* __restrict__ batch,
                            const float* __restrict__ Wd,   // [DD][CC]
                            float* __restrict__ score) {    // [GG][CC]
    __shared__ float ss[GG * CC];
    __shared__ float sW[DD * CC];
    const int tid = threadIdx.x;
    for (int i = tid; i < GG * CC; i += 256) ss[i] = 0.f;
    if (tid < DD * CC) sW[tid] = Wd[tid];
    __syncthreads();

    const int d = tid & 31;
    const int grp = tid >> 5;                  // 0..7
    const int n0 = blockIdx.x * 512;
    const int n1 = (n0 + 512 < NN) ? (n0 + 512) : NN;

    for (int n = n0 + grp; n < n1; n += 8) {
        float v = h[(size_t)n * DD + d];
        float p0 = v * sW[d * CC + 0];
        float p1 = v * sW[d * CC + 1];
        #pragma unroll
        for (int off = 16; off > 0; off >>= 1) {
            p0 += __shfl_xor(p0, off, 32);
            p1 += __shfl_xor(p1, off, 32);
        }
        if (d == 0) {
            int g = batch[n];
            atomicAdd(&ss[g * CC + 0], p0);
            atomicAdd(&ss[g * CC + 1], p1);
        }
    }
    __syncthreads();

    for (int i = tid; i < GG * CC; i += 256) {
        float v = ss[i];
        if (v != 0.f) atomicAdd(&score[i], v);
    }
}

// ---------------------------------------------------------------------------
// Final: add summed per-level biases, softmax over C=2.
// ---------------------------------------------------------------------------
__global__ void softmax_kernel(const float* __restrict__ score,
                               const float* __restrict__ db,   // [(NL+1)][CC]
                               float* __restrict__ out) {
    int g = blockIdx.x * blockDim.x + threadIdx.x;
    if (g >= GG) return;
    float bs0 = 0.f, bs1 = 0.f;
    #pragma unroll
    for (int i = 0; i <= NLAYERS; ++i) {
        bs0 += db[i * CC + 0];
        bs1 += db[i * CC + 1];
    }
    float s0 = score[g * CC + 0] + bs0;
    float s1 = score[g * CC + 1] + bs1;
    float m = fmaxf(s0, s1);
    float e0 = expf(s0 - m), e1 = expf(s1 - m);
    float inv = 1.f / (e0 + e1);
    out[g * CC + 0] = e0 * inv;
    out[g * CC + 1] = e1 * inv;
}

extern "C" void kernel_launch(void* const* d_in, const int* in_sizes, int n_in,
                              void* d_out, int out_size, void* d_ws, size_t ws_size,
                              hipStream_t stream) {
    (void)in_sizes; (void)n_in; (void)out_size; (void)ws_size;

    const float* node_emb = (const float*)d_in[0];
    const int*   ei       = (const int*)d_in[1];    // [2][EE]
    const int*   batch    = (const int*)d_in[2];
    const float* W1       = (const float*)d_in[3];  // [NL][D][D]
    const float* b1       = (const float*)d_in[4];
    const float* g1       = (const float*)d_in[5];
    const float* bt1      = (const float*)d_in[6];
    const float* W2       = (const float*)d_in[7];
    const float* b2       = (const float*)d_in[8];
    const float* g2       = (const float*)d_in[9];
    const float* bt2      = (const float*)d_in[10];
    const float* ng       = (const float*)d_in[11];
    const float* nb       = (const float*)d_in[12];
    const float* dW       = (const float*)d_in[13]; // [NL+1][D][C]
    const float* db       = (const float*)d_in[14]; // [NL+1][C]
    float* out = (float*)d_out;

    float* h     = (float*)d_ws;                    // [NN][DD]
    float* agg   = h + (size_t)NN * DD;             // [NN][DD]
    float* score = agg + (size_t)NN * DD;           // [GG][CC]

    hipMemcpyAsync(h, node_emb, (size_t)NN * DD * sizeof(float),
                   hipMemcpyDeviceToDevice, stream);
    hipMemsetAsync(score, 0, GG * CC * sizeof(float), stream);

    const int poolGrid = (NN + 511) / 512;          // 196

    // hidden level 0 (input embeddings)
    pool_kernel<<<poolGrid, 256, 0, stream>>>(h, batch, dW, score);

    for (int i = 0; i < NLAYERS; ++i) {
        hipMemsetAsync(agg, 0, (size_t)NN * DD * sizeof(float), stream);
        scatter_kernel<<<(EE * DD) / 256, 256, 0, stream>>>(h, ei, agg);
        node_update_kernel<<<2048, 256, 0, stream>>>(
            h, agg,
            W1 + (size_t)i * DD * DD, b1 + i * DD, g1 + i * DD, bt1 + i * DD,
            W2 + (size_t)i * DD * DD, b2 + i * DD, g2 + i * DD, bt2 + i * DD,
            ng + i * DD, nb + i * DD);
        pool_kernel<<<poolGrid, 256, 0, stream>>>(
            h, batch, dW + (size_t)(i + 1) * DD * CC, score);
    }

    softmax_kernel<<<(GG + 255) / 256, 256, 0, stream>>>(score, db, out);
}

// Round 2
// 637.761 us; speedup vs baseline: 1.5428x; 1.5428x over previous
//
#include <hip/hip_runtime.h>

#define NN 100000
#define EE 1600000
#define DD 32
#define CC 2
#define NLAYERS 4
#define GG 512
#define SCAN_BLK 1024
#define NSCAN ((NN + SCAN_BLK - 1) / SCAN_BLK)   // 98

// ---------------------------------------------------------------------------
// CSR-by-dst build: histogram -> 2-level exclusive scan -> atomic-cursor fill
// ---------------------------------------------------------------------------
__global__ void hist_kernel(const int* __restrict__ ei, int* __restrict__ deg) {
    int e = blockIdx.x * blockDim.x + threadIdx.x;
    if (e < EE) atomicAdd(&deg[ei[EE + e]], 1);
}

__global__ void scan1_kernel(const int* __restrict__ deg,
                             int* __restrict__ excl, int* __restrict__ sums) {
    __shared__ int a[2][SCAN_BLK];
    const int t = threadIdx.x;
    const int i = blockIdx.x * SCAN_BLK + t;
    int x = (i < NN) ? deg[i] : 0;
    a[0][t] = x;
    __syncthreads();
    int cur = 0;
    for (int off = 1; off < SCAN_BLK; off <<= 1) {
        int v = a[cur][t];
        if (t >= off) v += a[cur][t - off];
        a[cur ^ 1][t] = v;
        cur ^= 1;
        __syncthreads();
    }
    if (i < NN) excl[i] = a[cur][t] - x;           // exclusive within block
    if (t == SCAN_BLK - 1) sums[blockIdx.x] = a[cur][t];
}

__global__ void scan2_kernel(int* __restrict__ sums) {
    if (threadIdx.x == 0 && blockIdx.x == 0) {
        int off = 0;
        for (int b = 0; b < NSCAN; ++b) { int t = sums[b]; sums[b] = off; off += t; }
    }
}

__global__ void scan3_kernel(const int* __restrict__ excl,
                             const int* __restrict__ sums,
                             int* __restrict__ row_ptr, int* __restrict__ cursor) {
    int i = blockIdx.x * blockDim.x + threadIdx.x;
    if (i < NN) {
        int v = excl[i] + sums[i / SCAN_BLK];
        row_ptr[i] = v;
        cursor[i]  = v;
    }
    if (i == 0) row_ptr[NN] = EE;
}

__global__ void fill_kernel(const int* __restrict__ ei,
                            int* __restrict__ cursor, int* __restrict__ csr_src) {
    int e = blockIdx.x * blockDim.x + threadIdx.x;
    if (e < EE) {
        int s  = ei[e];
        int dn = ei[EE + e];
        int pos = atomicAdd(&cursor[dn], 1);
        csr_src[pos] = s;
    }
}

// ---------------------------------------------------------------------------
// Fused GIN layer: per node n (32 lanes = 32 dims):
//   acc = h_in[n] + sum_{e in CSR[n]} h_in[src[e]]      (gather, no atomics)
//   MLP: relu(bn1(acc@W1+b1)) @ W2 + b2 -> relu(bn2) -> relu(bn_out)
//   h_out[n] = w;  pooled readout: score[batch[n]] += w @ dWl  (LDS image)
// 256 threads = 8 nodes/iter, 16 iters -> 128 contiguous nodes per block.
// ---------------------------------------------------------------------------
__global__ void layer_kernel(const float* __restrict__ h_in,
                             float* __restrict__ h_out,
                             const int* __restrict__ row_ptr,
                             const int* __restrict__ csr_src,
                             const int* __restrict__ batch,
                             const float* __restrict__ W1,
                             const float* __restrict__ b1,
                             const float* __restrict__ g1,
                             const float* __restrict__ bt1,
                             const float* __restrict__ W2,
                             const float* __restrict__ b2,
                             const float* __restrict__ g2,
                             const float* __restrict__ bt2,
                             const float* __restrict__ ng,
                             const float* __restrict__ nb,
                             const float* __restrict__ dWl,  // [DD][CC] readout for this level
                             float* __restrict__ score) {
    __shared__ float sW1[DD * DD];
    __shared__ float sW2[DD * DD];
    __shared__ float sp[8 * DD];
    __shared__ float sdW[DD * CC];
    __shared__ float ss[GG * CC];
    __shared__ float z1[8][DD];
    __shared__ float z2[8][DD];

    const int tid = threadIdx.x;
    for (int i = tid; i < DD * DD; i += 256) {
        sW1[i] = W1[i];
        sW2[i] = W2[i];
    }
    if (tid < DD) {
        sp[0 * DD + tid] = b1[tid];
        sp[1 * DD + tid] = g1[tid];
        sp[2 * DD + tid] = bt1[tid];
        sp[3 * DD + tid] = b2[tid];
        sp[4 * DD + tid] = g2[tid];
        sp[5 * DD + tid] = bt2[tid];
        sp[6 * DD + tid] = ng[tid];
        sp[7 * DD + tid] = nb[tid];
    }
    if (tid < DD * CC) sdW[tid] = dWl[tid];
    for (int i = tid; i < GG * CC; i += 256) ss[i] = 0.f;
    __syncthreads();

    const float invs = 1.0f / sqrtf(1.001f);   // BN inference: mean=0,var=1,eps=1e-3
    const int j = tid >> 5;        // node slot 0..7
    const int d = tid & 31;        // dim
    const int base = blockIdx.x * 128;

    for (int it = 0; it < 16; ++it) {
        const int n = base + it * 8 + j;
        const bool ok = (n < NN);
        float acc = 0.f;
        if (ok) {
            acc = h_in[(size_t)n * DD + d];       // (1+eps)*h, eps=0
            int e  = row_ptr[n];
            const int e1 = row_ptr[n + 1];
            for (; e + 4 <= e1; e += 4) {         // unrolled gather
                int s0 = csr_src[e + 0];
                int s1 = csr_src[e + 1];
                int s2 = csr_src[e + 2];
                int s3 = csr_src[e + 3];
                float v0 = h_in[(size_t)s0 * DD + d];
                float v1 = h_in[(size_t)s1 * DD + d];
                float v2 = h_in[(size_t)s2 * DD + d];
                float v3 = h_in[(size_t)s3 * DD + d];
                acc += v0 + v1 + v2 + v3;
            }
            for (; e < e1; ++e)
                acc += h_in[(size_t)csr_src[e] * DD + d];
        }
        z1[j][d] = acc;
        __syncthreads();

        float a1 = sp[0 * DD + d];
        #pragma unroll
        for (int k = 0; k < DD; ++k)
            a1 += z1[j][k] * sW1[k * DD + d];
        float v = a1 * (sp[1 * DD + d] * invs) + sp[2 * DD + d];
        v = fmaxf(v, 0.f);
        z2[j][d] = v;
        __syncthreads();

        float a2 = sp[3 * DD + d];
        #pragma unroll
        for (int k = 0; k < DD; ++k)
            a2 += z2[j][k] * sW2[k * DD + d];
        float w = a2 * (sp[4 * DD + d] * invs) + sp[5 * DD + d];
        w = fmaxf(w, 0.f);
        w = w * (sp[6 * DD + d] * invs) + sp[7 * DD + d];
        w = fmaxf(w, 0.f);

        // fused pooled readout
        float p0 = w * sdW[d * CC + 0];
        float p1 = w * sdW[d * CC + 1];
        #pragma unroll
        for (int off = 16; off > 0; off >>= 1) {
            p0 += __shfl_xor(p0, off, 32);
            p1 += __shfl_xor(p1, off, 32);
        }
        if (ok) {
            h_out[(size_t)n * DD + d] = w;
            if (d == 0) {
                int g = batch[n];
                atomicAdd(&ss[g * CC + 0], p0);
                atomicAdd(&ss[g * CC + 1], p1);
            }
        }
        __syncthreads();   // protect z1/z2 reuse across iterations
    }

    for (int i = tid; i < GG * CC; i += 256) {
        float v = ss[i];
        if (v != 0.f) atomicAdd(&score[i], v);
    }
}

// ---------------------------------------------------------------------------
// Pool + readout for hidden level 0 (raw embeddings)
// ---------------------------------------------------------------------------
__global__ void pool_kernel(const float* __restrict__ h,
                            const int* __restrict__ batch,
                            const float* __restrict__ Wd,
                            float* __restrict__ score) {
    __shared__ float ss[GG * CC];
    __shared__ float sW[DD * CC];
    const int tid = threadIdx.x;
    for (int i = tid; i < GG * CC; i += 256) ss[i] = 0.f;
    if (tid < DD * CC) sW[tid] = Wd[tid];
    __syncthreads();

    const int d = tid & 31;
    const int grp = tid >> 5;
    const int n0 = blockIdx.x * 512;
    const int n1 = (n0 + 512 < NN) ? (n0 + 512) : NN;

    for (int n = n0 + grp; n < n1; n += 8) {
        float v = h[(size_t)n * DD + d];
        float p0 = v * sW[d * CC + 0];
        float p1 = v * sW[d * CC + 1];
        #pragma unroll
        for (int off = 16; off > 0; off >>= 1) {
            p0 += __shfl_xor(p0, off, 32);
            p1 += __shfl_xor(p1, off, 32);
        }
        if (d == 0) {
            int g = batch[n];
            atomicAdd(&ss[g * CC + 0], p0);
            atomicAdd(&ss[g * CC + 1], p1);
        }
    }
    __syncthreads();

    for (int i = tid; i < GG * CC; i += 256) {
        float v = ss[i];
        if (v != 0.f) atomicAdd(&score[i], v);
    }
}

__global__ void softmax_kernel(const float* __restrict__ score,
                               const float* __restrict__ db,
                               float* __restrict__ out) {
    int g = blockIdx.x * blockDim.x + threadIdx.x;
    if (g >= GG) return;
    float bs0 = 0.f, bs1 = 0.f;
    #pragma unroll
    for (int i = 0; i <= NLAYERS; ++i) {
        bs0 += db[i * CC + 0];
        bs1 += db[i * CC + 1];
    }
    float s0 = score[g * CC + 0] + bs0;
    float s1 = score[g * CC + 1] + bs1;
    float m = fmaxf(s0, s1);
    float e0 = expf(s0 - m), e1 = expf(s1 - m);
    float inv = 1.f / (e0 + e1);
    out[g * CC + 0] = e0 * inv;
    out[g * CC + 1] = e1 * inv;
}

extern "C" void kernel_launch(void* const* d_in, const int* in_sizes, int n_in,
                              void* d_out, int out_size, void* d_ws, size_t ws_size,
                              hipStream_t stream) {
    (void)in_sizes; (void)n_in; (void)out_size; (void)ws_size;

    const float* node_emb = (const float*)d_in[0];
    const int*   ei       = (const int*)d_in[1];
    const int*   batch    = (const int*)d_in[2];
    const float* W1       = (const float*)d_in[3];
    const float* b1       = (const float*)d_in[4];
    const float* g1       = (const float*)d_in[5];
    const float* bt1      = (const float*)d_in[6];
    const float* W2       = (const float*)d_in[7];
    const float* b2       = (const float*)d_in[8];
    const float* g2       = (const float*)d_in[9];
    const float* bt2      = (const float*)d_in[10];
    const float* ng       = (const float*)d_in[11];
    const float* nb       = (const float*)d_in[12];
    const float* dW       = (const float*)d_in[13];
    const float* db       = (const float*)d_in[14];
    float* out = (float*)d_out;

    // workspace layout
    float* hA    = (float*)d_ws;                 // [NN][DD]
    float* hB    = hA + (size_t)NN * DD;         // [NN][DD]
    float* score = hB + (size_t)NN * DD;         // [GG][CC]
    int* deg     = (int*)(score + GG * CC);      // [NN]
    int* excl    = deg + NN;                     // [NN]
    int* sums    = excl + NN;                    // [NSCAN] (pad to 128)
    int* row_ptr = sums + 128;                   // [NN+1]
    int* cursor  = row_ptr + NN + 2;             // [NN]
    int* csr_src = cursor + NN;                  // [EE]

    hipMemsetAsync(deg, 0, NN * sizeof(int), stream);
    hipMemsetAsync(score, 0, GG * CC * sizeof(float), stream);

    // CSR build (once per launch)
    hist_kernel<<<(EE + 255) / 256, 256, 0, stream>>>(ei, deg);
    scan1_kernel<<<NSCAN, SCAN_BLK, 0, stream>>>(deg, excl, sums);
    scan2_kernel<<<1, 64, 0, stream>>>(sums);
    scan3_kernel<<<(NN + 255) / 256, 256, 0, stream>>>(excl, sums, row_ptr, cursor);
    fill_kernel<<<(EE + 255) / 256, 256, 0, stream>>>(ei, cursor, csr_src);

    // hidden level 0 readout on raw embeddings
    pool_kernel<<<(NN + 511) / 512, 256, 0, stream>>>(node_emb, batch, dW, score);

    const int layerGrid = (NN + 127) / 128;      // 782
    const float* cur_in = node_emb;
    float* bufs[2] = {hA, hB};
    for (int i = 0; i < NLAYERS; ++i) {
        float* o = bufs[i & 1];
        layer_kernel<<<layerGrid, 256, 0, stream>>>(
            cur_in, o, row_ptr, csr_src, batch,
            W1 + (size_t)i * DD * DD, b1 + i * DD, g1 + i * DD, bt1 + i * DD,
            W2 + (size_t)i * DD * DD, b2 + i * DD, g2 + i * DD, bt2 + i * DD,
            ng + i * DD, nb + i * DD,
            dW + (size_t)(i + 1) * DD * CC, score);
        cur_in = o;
    }

    softmax_kernel<<<(GG + 255) / 256, 256, 0, stream>>>(score, db, out);
}

// Round 3
// 467.420 us; speedup vs baseline: 2.1051x; 1.3644x over previous
//
#include <hip/hip_runtime.h>

#define NN 100000
#define EE 1600000
#define DD 32
#define CC 2
#define NLAYERS 4
#define GG 512

#define BW 1024                       // nodes per dst-bucket
#define NBUK ((NN + BW - 1) / BW)     // 98
#define CAP 24576                     // per-bucket staging capacity (mean 16327)
#define CH 8192                       // edges per partition block
#define NPART ((EE + CH - 1) / CH)    // 196

// ---------------------------------------------------------------------------
// Phase 1: partition edges into NBUK dst-range buckets. LDS-staged so the
// global writes are coalesced runs. Packs (dst_local<<17 | src) into 4B
// (src < 2^17, dst_local < 2^10).
// ---------------------------------------------------------------------------
__global__ void part_kernel(const int* __restrict__ ei,
                            int* __restrict__ gcur,
                            unsigned* __restrict__ part) {
    __shared__ unsigned sorted[CH];        // 32 KB
    __shared__ unsigned char sbkt[CH];     // 8 KB
    __shared__ int cnt[NBUK], offs[NBUK], cur[NBUK], gbs[NBUK];

    const int tid = threadIdx.x;
    const int eb  = blockIdx.x * CH;
    const int nch = min(CH, EE - eb);

    for (int b = tid; b < NBUK; b += 256) cnt[b] = 0;
    __syncthreads();
    for (int i = tid; i < nch; i += 256) {
        int dn = ei[EE + eb + i];
        atomicAdd(&cnt[dn >> 10], 1);
    }
    __syncthreads();
    if (tid == 0) {
        int o = 0;
        for (int b = 0; b < NBUK; ++b) { offs[b] = o; o += cnt[b]; }
    }
    __syncthreads();
    if (tid < NBUK) {
        cur[tid] = offs[tid];
        gbs[tid] = cnt[tid] ? atomicAdd(&gcur[tid], cnt[tid]) : 0;
    }
    __syncthreads();
    for (int i = tid; i < nch; i += 256) {
        int s  = ei[eb + i];
        int dn = ei[EE + eb + i];
        int b  = dn >> 10;
        unsigned pk = ((unsigned)(dn & (BW - 1)) << 17) | (unsigned)s;
        int p = atomicAdd(&cur[b], 1);
        sorted[p] = pk;
        sbkt[p]   = (unsigned char)b;
    }
    __syncthreads();
    for (int i = tid; i < nch; i += 256) {
        int b = sbkt[i];
        part[(size_t)b * CAP + gbs[b] + (i - offs[b])] = sorted[i];
    }
}

// Phase 2: exclusive scan of 98 bucket counts (trivial).
__global__ void bscan_kernel(const int* __restrict__ gcur,
                             int* __restrict__ bbase,
                             int* __restrict__ row_ptr) {
    if (threadIdx.x == 0 && blockIdx.x == 0) {
        int o = 0;
        for (int b = 0; b < NBUK; ++b) { bbase[b] = o; o += gcur[b]; }
        row_ptr[NN] = EE;
    }
}

// ---------------------------------------------------------------------------
// Phase 3: per-bucket local CSR. Histogram + scan of 1024 nodes in LDS; fill
// writes land in one contiguous ~64KB region -> L2-resident, no write amp.
// ---------------------------------------------------------------------------
__global__ void lcsr_kernel(const unsigned* __restrict__ part,
                            const int* __restrict__ gcur,
                            const int* __restrict__ bbase,
                            int* __restrict__ row_ptr,
                            int* __restrict__ csr_src) {
    __shared__ int hcnt[BW];
    __shared__ int a[2][BW];
    __shared__ int ccur[BW];
    const int t    = threadIdx.x;
    const int b    = blockIdx.x;
    const int cntb = gcur[b];
    const int base = bbase[b];
    const size_t pb = (size_t)b * CAP;

    hcnt[t] = 0;
    __syncthreads();
    for (int i = t; i < cntb; i += BW)
        atomicAdd(&hcnt[part[pb + i] >> 17], 1);
    __syncthreads();
    int x = hcnt[t];
    a[0][t] = x;
    __syncthreads();
    int cb = 0;
    for (int off = 1; off < BW; off <<= 1) {
        int v = a[cb][t];
        if (t >= off) v += a[cb][t - off];
        a[cb ^ 1][t] = v;
        cb ^= 1;
        __syncthreads();
    }
    const int excl = a[cb][t] - x;
    const int node = b * BW + t;
    if (node < NN) row_ptr[node] = base + excl;
    ccur[t] = excl;
    __syncthreads();
    for (int i = t; i < cntb; i += BW) {
        unsigned pk = part[pb + i];
        int dl  = pk >> 17;
        int pos = base + atomicAdd(&ccur[dl], 1);
        csr_src[pos] = (int)(pk & 0x1FFFFu);
    }
}

// ---------------------------------------------------------------------------
// Fused GIN layer. Block = 128 nodes. Phase 1: each 32-lane group gathers 16
// nodes into zA (stragglers average out, no barriers). ONE barrier. Phase 2:
// MLP with weights in registers, z broadcast from LDS as float4, z2 exchange
// within-wave -> zero barriers. Fused pooled readout into LDS score image.
// ---------------------------------------------------------------------------
__global__ __launch_bounds__(256) void layer_kernel(
    const float* __restrict__ h_in, float* __restrict__ h_out,
    const int* __restrict__ row_ptr, const int* __restrict__ csr_src,
    const int* __restrict__ batch,
    const float* __restrict__ W1, const float* __restrict__ b1,
    const float* __restrict__ g1, const float* __restrict__ bt1,
    const float* __restrict__ W2, const float* __restrict__ b2,
    const float* __restrict__ g2, const float* __restrict__ bt2,
    const float* __restrict__ ng, const float* __restrict__ nb,
    const float* __restrict__ dWl, float* __restrict__ score) {
    __shared__ float sp[8 * DD];
    __shared__ float sdW[DD * CC];
    __shared__ float ss[GG * CC];
    __shared__ float zA[128][DD];      // 16 KB
    __shared__ float z2loc[8][DD];     // 1 KB

    const int tid = threadIdx.x;
    const int j = tid >> 5;
    const int d = tid & 31;

    float w1r[DD], w2r[DD];
    #pragma unroll
    for (int k = 0; k < DD; ++k) w1r[k] = W1[k * DD + d];
    #pragma unroll
    for (int k = 0; k < DD; ++k) w2r[k] = W2[k * DD + d];

    if (tid < DD) {
        sp[0 * DD + tid] = b1[tid];
        sp[1 * DD + tid] = g1[tid];
        sp[2 * DD + tid] = bt1[tid];
        sp[3 * DD + tid] = b2[tid];
        sp[4 * DD + tid] = g2[tid];
        sp[5 * DD + tid] = bt2[tid];
        sp[6 * DD + tid] = ng[tid];
        sp[7 * DD + tid] = nb[tid];
    }
    if (tid < DD * CC) sdW[tid] = dWl[tid];
    for (int i = tid; i < GG * CC; i += 256) ss[i] = 0.f;

    const float invs = 1.0f / sqrtf(1.001f);   // BN: mean=0, var=1, eps=1e-3
    const int base = blockIdx.x * 128;

    // phase 1: gather (no intra-phase barriers)
    for (int s = 0; s < 16; ++s) {
        const int n = base + j * 16 + s;
        if (n < NN) {
            float acc = h_in[(size_t)n * DD + d];
            int e = row_ptr[n];
            const int e1 = row_ptr[n + 1];
            for (; e + 4 <= e1; e += 4) {
                int s0 = csr_src[e + 0];
                int s1 = csr_src[e + 1];
                int s2 = csr_src[e + 2];
                int s3 = csr_src[e + 3];
                float v0 = h_in[(size_t)s0 * DD + d];
                float v1 = h_in[(size_t)s1 * DD + d];
                float v2 = h_in[(size_t)s2 * DD + d];
                float v3 = h_in[(size_t)s3 * DD + d];
                acc += v0 + v1 + v2 + v3;
            }
            for (; e < e1; ++e)
                acc += h_in[(size_t)csr_src[e] * DD + d];
            zA[j * 16 + s][d] = acc;
        }
    }
    __syncthreads();

    // phase 2: MLP + fused pool (no barriers; z2loc stays within one wave)
    for (int s = 0; s < 16; ++s) {
        const int n = base + j * 16 + s;
        if (n >= NN) break;                 // uniform within the 32-lane group
        const int local = j * 16 + s;

        float a1 = sp[0 * DD + d];
        #pragma unroll
        for (int kk = 0; kk < DD; kk += 4) {
            const float4 zv = *reinterpret_cast<const float4*>(&zA[local][kk]);
            a1 += zv.x * w1r[kk] + zv.y * w1r[kk + 1] +
                  zv.z * w1r[kk + 2] + zv.w * w1r[kk + 3];
        }
        float v = fmaxf(a1 * (sp[1 * DD + d] * invs) + sp[2 * DD + d], 0.f);
        z2loc[j][d] = v;                    // within-wave exchange (in-order LDS)

        float a2 = sp[3 * DD + d];
        #pragma unroll
        for (int kk = 0; kk < DD; kk += 4) {
            const float4 zv = *reinterpret_cast<const float4*>(&z2loc[j][kk]);
            a2 += zv.x * w2r[kk] + zv.y * w2r[kk + 1] +
                  zv.z * w2r[kk + 2] + zv.w * w2r[kk + 3];
        }
        float w = fmaxf(a2 * (sp[4 * DD + d] * invs) + sp[5 * DD + d], 0.f);
        w = fmaxf(w * (sp[6 * DD + d] * invs) + sp[7 * DD + d], 0.f);
        h_out[(size_t)n * DD + d] = w;

        float p0 = w * sdW[d * CC + 0];
        float p1 = w * sdW[d * CC + 1];
        #pragma unroll
        for (int off = 16; off > 0; off >>= 1) {
            p0 += __shfl_xor(p0, off, 32);
            p1 += __shfl_xor(p1, off, 32);
        }
        if (d == 0) {
            int g = batch[n];
            atomicAdd(&ss[g * CC + 0], p0);
            atomicAdd(&ss[g * CC + 1], p1);
        }
    }
    __syncthreads();

    for (int i = tid; i < GG * CC; i += 256) {
        float v = ss[i];
        if (v != 0.f) atomicAdd(&score[i], v);
    }
}

// ---------------------------------------------------------------------------
// Pool + readout for hidden level 0 (raw embeddings)
// ---------------------------------------------------------------------------
__global__ void pool_kernel(const float* __restrict__ h,
                            const int* __restrict__ batch,
                            const float* __restrict__ Wd,
                            float* __restrict__ score) {
    __shared__ float ss[GG * CC];
    __shared__ float sW[DD * CC];
    const int tid = threadIdx.x;
    for (int i = tid; i < GG * CC; i += 256) ss[i] = 0.f;
    if (tid < DD * CC) sW[tid] = Wd[tid];
    __syncthreads();

    const int d = tid & 31;
    const int grp = tid >> 5;
    const int n0 = blockIdx.x * 512;
    const int n1 = (n0 + 512 < NN) ? (n0 + 512) : NN;

    for (int n = n0 + grp; n < n1; n += 8) {
        float v = h[(size_t)n * DD + d];
        float p0 = v * sW[d * CC + 0];
        float p1 = v * sW[d * CC + 1];
        #pragma unroll
        for (int off = 16; off > 0; off >>= 1) {
            p0 += __shfl_xor(p0, off, 32);
            p1 += __shfl_xor(p1, off, 32);
        }
        if (d == 0) {
            int g = batch[n];
            atomicAdd(&ss[g * CC + 0], p0);
            atomicAdd(&ss[g * CC + 1], p1);
        }
    }
    __syncthreads();

    for (int i = tid; i < GG * CC; i += 256) {
        float v = ss[i];
        if (v != 0.f) atomicAdd(&score[i], v);
    }
}

__global__ void softmax_kernel(const float* __restrict__ score,
                               const float* __restrict__ db,
                               float* __restrict__ out) {
    int g = blockIdx.x * blockDim.x + threadIdx.x;
    if (g >= GG) return;
    float bs0 = 0.f, bs1 = 0.f;
    #pragma unroll
    for (int i = 0; i <= NLAYERS; ++i) {
        bs0 += db[i * CC + 0];
        bs1 += db[i * CC + 1];
    }
    float s0 = score[g * CC + 0] + bs0;
    float s1 = score[g * CC + 1] + bs1;
    float m = fmaxf(s0, s1);
    float e0 = expf(s0 - m), e1 = expf(s1 - m);
    float inv = 1.f / (e0 + e1);
    out[g * CC + 0] = e0 * inv;
    out[g * CC + 1] = e1 * inv;
}

extern "C" void kernel_launch(void* const* d_in, const int* in_sizes, int n_in,
                              void* d_out, int out_size, void* d_ws, size_t ws_size,
                              hipStream_t stream) {
    (void)in_sizes; (void)n_in; (void)out_size; (void)ws_size;

    const float* node_emb = (const float*)d_in[0];
    const int*   ei       = (const int*)d_in[1];
    const int*   batch    = (const int*)d_in[2];
    const float* W1       = (const float*)d_in[3];
    const float* b1       = (const float*)d_in[4];
    const float* g1       = (const float*)d_in[5];
    const float* bt1      = (const float*)d_in[6];
    const float* W2       = (const float*)d_in[7];
    const float* b2       = (const float*)d_in[8];
    const float* g2       = (const float*)d_in[9];
    const float* bt2      = (const float*)d_in[10];
    const float* ng       = (const float*)d_in[11];
    const float* nb       = (const float*)d_in[12];
    const float* dW       = (const float*)d_in[13];
    const float* db       = (const float*)d_in[14];
    float* out = (float*)d_out;

    // workspace layout (part[] aliases hB: hB is first written by layer 2,
    // long after lcsr has consumed part[])
    float* hA      = (float*)d_ws;                    // [NN][DD] 12.8MB
    float* hB      = hA + (size_t)NN * DD;            // [NN][DD] 12.8MB
    unsigned* part = (unsigned*)hB;                   // [NBUK][CAP] 9.6MB alias
    float* score   = hB + (size_t)NN * DD;            // [GG][CC]
    int* row_ptr   = (int*)(score + GG * CC);         // [NN+1]
    int* csr_src   = row_ptr + NN + 2;                // [EE] 6.4MB
    int* gcur      = csr_src + EE;                    // [128]
    int* bbase     = gcur + 128;                      // [128]

    hipMemsetAsync(gcur, 0, 128 * sizeof(int), stream);
    hipMemsetAsync(score, 0, GG * CC * sizeof(float), stream);

    // CSR build (cache-local, ~3 kernels)
    part_kernel<<<NPART, 256, 0, stream>>>(ei, gcur, part);
    bscan_kernel<<<1, 64, 0, stream>>>(gcur, bbase, row_ptr);
    lcsr_kernel<<<NBUK, BW, 0, stream>>>(part, gcur, bbase, row_ptr, csr_src);

    // hidden level 0 readout on raw embeddings
    pool_kernel<<<(NN + 511) / 512, 256, 0, stream>>>(node_emb, batch, dW, score);

    const int layerGrid = (NN + 127) / 128;           // 782
    const float* cur_in = node_emb;
    float* bufs[2] = {hA, hB};
    for (int i = 0; i < NLAYERS; ++i) {
        float* o = bufs[i & 1];
        layer_kernel<<<layerGrid, 256, 0, stream>>>(
            cur_in, o, row_ptr, csr_src, batch,
            W1 + (size_t)i * DD * DD, b1 + i * DD, g1 + i * DD, bt1 + i * DD,
            W2 + (size_t)i * DD * DD, b2 + i * DD, g2 + i * DD, bt2 + i * DD,
            ng + i * DD, nb + i * DD,
            dW + (size_t)(i + 1) * DD * CC, score);
        cur_in = o;
    }

    softmax_kernel<<<(GG + 255) / 256, 256, 0, stream>>>(score, db, out);
}